// Round 3
// baseline (512.537 us; speedup 1.0000x reference)
//
#include <hip/hip_runtime.h>
#include <math.h>

// ---- problem constants (match reference) ----
#define NN   100000   // nodes
#define DD   128      // in_channels
#define EE   600000   // edges
#define EAD  16       // edge_attr dim
#define BB   50       // graphs
#define NPG  2000     // nodes per graph
#define KK   1000     // kept per graph
#define NKEEP (BB*KK) // 50000

// output layout (floats, concatenated in return order)
#define OFF_OEI    6400000
#define OFF_OEA    7600000
#define OFF_OBATCH 17200000
#define OFF_EMASK  17250000

#define NRED 240  // reduction blocks
#define SCAN_NB 98 // ceil(100000/1024)

// ============ K1: edge MLP -> ew, deg_w, deg_c ============
__global__ __launch_bounds__(256) void k_edge_mlp(
    const float* __restrict__ edge_attr, const int* __restrict__ src,
    const float* __restrict__ We1, const float* __restrict__ be1,
    const float* __restrict__ We2, const float* __restrict__ be2,
    float* __restrict__ ew, float* __restrict__ deg_w, float* __restrict__ deg_c)
{
    int e = blockIdx.x * 256 + threadIdx.x;
    if (e >= EE) return;
    const float4* ap = (const float4*)(edge_attr + (size_t)e * EAD);
    float4 a0 = ap[0], a1 = ap[1], a2 = ap[2], a3 = ap[3];
    float ea[16] = {a0.x,a0.y,a0.z,a0.w, a1.x,a1.y,a1.z,a1.w,
                    a2.x,a2.y,a2.z,a2.w, a3.x,a3.y,a3.z,a3.w};
    float acc = be2[0];
    for (int j = 0; j < DD; j++) {
        float h = be1[j];
        #pragma unroll
        for (int k = 0; k < 16; k++) h += ea[k] * We1[k*DD + j];
        acc += fmaxf(h, 0.f) * We2[j];
    }
    float sp = fmaxf(acc, 0.f) + log1pf(expf(-fabsf(acc)));
    float w = sp + 1e-6f;
    ew[e] = w;
    int s = src[e];
    atomicAdd(&deg_w[s], w);
    atomicAdd(&deg_c[s], 1.0f);
}

// ============ K2: dis = deg_w^-0.5 ============
__global__ __launch_bounds__(256) void k_dis(const float* __restrict__ deg_w,
                                             float* __restrict__ dis)
{
    int n = blockIdx.x * 256 + threadIdx.x;
    if (n >= NN) return;
    float d = deg_w[n];
    dis[n] = d > 0.f ? 1.f / sqrtf(d) : 0.f;
}

// ============ K3a: per-1024-block exclusive scan of degree counts ============
__global__ __launch_bounds__(1024) void k_scan_block(
    const float* __restrict__ deg_c, int* __restrict__ scanned,
    int* __restrict__ blocksums)
{
    __shared__ int s[1024];
    int i = blockIdx.x * 1024 + threadIdx.x;
    int c = (i < NN) ? (int)deg_c[i] : 0;
    s[threadIdx.x] = c;
    __syncthreads();
    for (int off = 1; off < 1024; off <<= 1) {
        int v = (threadIdx.x >= off) ? s[threadIdx.x - off] : 0;
        __syncthreads();
        s[threadIdx.x] += v;
        __syncthreads();
    }
    if (i < NN) scanned[i] = s[threadIdx.x] - c; // exclusive
    if (threadIdx.x == 1023) blocksums[blockIdx.x] = s[1023];
}

// ============ K3b: scan the block sums (one block) ============
__global__ __launch_bounds__(128) void k_scan_top(int* __restrict__ blocksums)
{
    __shared__ int s[128];
    int c = (threadIdx.x < SCAN_NB) ? blocksums[threadIdx.x] : 0;
    s[threadIdx.x] = c;
    __syncthreads();
    for (int off = 1; off < 128; off <<= 1) {
        int v = (threadIdx.x >= off) ? s[threadIdx.x - off] : 0;
        __syncthreads();
        s[threadIdx.x] += v;
        __syncthreads();
    }
    if (threadIdx.x < SCAN_NB) blocksums[threadIdx.x] = s[threadIdx.x] - c; // exclusive
}

// ============ K3c: rowstart / cursor init ============
__global__ __launch_bounds__(256) void k_cursor(
    const int* __restrict__ scanned, const int* __restrict__ blocksums,
    int* __restrict__ rowstart, int* __restrict__ cur)
{
    int n = blockIdx.x * 256 + threadIdx.x;
    if (n >= NN) return;
    int st = scanned[n] + blocksums[n >> 10];
    rowstart[n] = st;
    cur[n] = st;
}

// ============ K3d: scatter edges into CSR buckets (dst + norm) ============
__global__ __launch_bounds__(256) void k_scatter(
    const int* __restrict__ src, const int* __restrict__ dst,
    const float* __restrict__ ew, const float* __restrict__ dis,
    int* __restrict__ cur, int* __restrict__ csr_dst, float* __restrict__ csr_w)
{
    int e = blockIdx.x * 256 + threadIdx.x;
    if (e >= EE) return;
    int s = src[e], d = dst[e];
    float w = dis[s] * ew[e] * dis[d];
    int pos = atomicAdd(&cur[s], 1);
    csr_dst[pos] = d;
    csr_w[pos] = w;
}

// ============ K3e: gather diffusion — one wave per node, no atomics ============
__global__ __launch_bounds__(256) void k_gather(
    const int* __restrict__ rowstart, const float* __restrict__ deg_c,
    const int* __restrict__ csr_dst, const float* __restrict__ csr_w,
    const float* __restrict__ x, float* __restrict__ x_diff)
{
    int wid = (blockIdx.x * 256 + threadIdx.x) >> 6; // node id (wave-uniform)
    int lane = threadIdx.x & 63;
    if (wid >= NN) return;
    int start = rowstart[wid];
    int end = start + (int)deg_c[wid];
    const float2* xp = (const float2*)x;
    float2 acc = {0.f, 0.f};
    for (int e = start; e < end; e++) {
        int d = csr_dst[e];
        float w = csr_w[e];
        float2 xv = xp[(size_t)d * 64 + lane];
        acc.x += xv.x * w;
        acc.y += xv.y * w;
    }
    ((float2*)x_diff)[(size_t)wid * 64 + lane] = acc;
}

// ============ K4: per-node feat MLP + cosine + log-degree ============
// Register-blocked: 64 lanes = 16 j-groups x 4 node-groups; each lane
// accumulates 4 nodes x 8 columns. Block = 4 waves = 64 nodes.
#define XSTR 132  // x row stride in LDS: %4==0 (float4), %32==4 (2-way conflicts only)
__global__ __launch_bounds__(256) void k_node(
    const float* __restrict__ x, const float* __restrict__ x_diff,
    const float* __restrict__ W1, const float* __restrict__ b1,
    const float* __restrict__ W2, const float* __restrict__ b2,
    const float* __restrict__ deg_c,
    float* __restrict__ raw0, float* __restrict__ raw1, float* __restrict__ raw2)
{
    __shared__ float xs[64 * XSTR]; // 33.8 KB
    int wave = threadIdx.x >> 6, lane = threadIdx.x & 63;
    int ng = lane >> 4, jg = lane & 15;
    int blockBase = blockIdx.x * 64;

    // stage 64 x rows into LDS (clamped for tail block)
    #pragma unroll
    for (int it = 0; it < 8; it++) {
        int s = threadIdx.x + 256 * it;       // 0..2047 float4 slots
        int row = s >> 5, c4 = s & 31;
        int gn = blockBase + row; if (gn >= NN) gn = NN - 1;
        *(float4*)(xs + row * XSTR + c4 * 4) =
            *(const float4*)(x + (size_t)gn * DD + c4 * 4);
    }
    __syncthreads();

    const float* xw = xs + (wave * 16 + ng * 4) * XSTR; // this lane's 4 node rows
    int j0 = jg * 8;
    float acc[4][8];
    #pragma unroll
    for (int i = 0; i < 4; i++)
        #pragma unroll
        for (int jj = 0; jj < 8; jj++) acc[i][jj] = 0.f;

    for (int k = 0; k < DD; k += 4) {
        float4 xv[4];
        #pragma unroll
        for (int i = 0; i < 4; i++) xv[i] = *(const float4*)(xw + i * XSTR + k);
        float4 wv[4][2];
        #pragma unroll
        for (int kk = 0; kk < 4; kk++) {
            wv[kk][0] = *(const float4*)(W1 + (k + kk) * DD + j0);
            wv[kk][1] = *(const float4*)(W1 + (k + kk) * DD + j0 + 4);
        }
        #pragma unroll
        for (int i = 0; i < 4; i++) {
            const float xe[4] = {xv[i].x, xv[i].y, xv[i].z, xv[i].w};
            #pragma unroll
            for (int kk = 0; kk < 4; kk++) {
                acc[i][0] += xe[kk] * wv[kk][0].x;
                acc[i][1] += xe[kk] * wv[kk][0].y;
                acc[i][2] += xe[kk] * wv[kk][0].z;
                acc[i][3] += xe[kk] * wv[kk][0].w;
                acc[i][4] += xe[kk] * wv[kk][1].x;
                acc[i][5] += xe[kk] * wv[kk][1].y;
                acc[i][6] += xe[kk] * wv[kk][1].z;
                acc[i][7] += xe[kk] * wv[kk][1].w;
            }
        }
    }

    // feat epilogue: relu(acc + b1) . W2, reduce across 16 j-groups
    float4 b1a = *(const float4*)(b1 + j0), b1b = *(const float4*)(b1 + j0 + 4);
    float4 w2a = *(const float4*)(W2 + j0), w2b = *(const float4*)(W2 + j0 + 4);
    const float b1v[8] = {b1a.x,b1a.y,b1a.z,b1a.w, b1b.x,b1b.y,b1b.z,b1b.w};
    const float w2v[8] = {w2a.x,w2a.y,w2a.z,w2a.w, w2b.x,w2b.y,w2b.z,w2b.w};
    float bias2 = b2[0];
    #pragma unroll
    for (int i = 0; i < 4; i++) {
        float p = 0.f;
        #pragma unroll
        for (int jj = 0; jj < 8; jj++)
            p += fmaxf(acc[i][jj] + b1v[jj], 0.f) * w2v[jj];
        p += __shfl_xor(p, 1, 64);
        p += __shfl_xor(p, 2, 64);
        p += __shfl_xor(p, 4, 64);
        p += __shfl_xor(p, 8, 64);
        int node = blockBase + wave * 16 + ng * 4 + i;
        if (jg == 0 && node < NN) raw1[node] = p + bias2;
    }

    // cosine view: 16 nodes per wave, full-wave reduction
    const float* xwv = xs + wave * 16 * XSTR;
    #pragma unroll 1
    for (int nd = 0; nd < 16; nd++) {
        int node = blockBase + wave * 16 + nd;
        int rn = node < NN ? node : NN - 1;
        float2 xv2 = *(const float2*)(xwv + nd * XSTR + lane * 2);
        float2 xd2 = *(const float2*)(x_diff + (size_t)rn * DD + lane * 2);
        float dot = xv2.x * xd2.x + xv2.y * xd2.y;
        float nx  = xv2.x * xv2.x + xv2.y * xv2.y;
        float ndn = xd2.x * xd2.x + xd2.y * xd2.y;
        #pragma unroll
        for (int off = 32; off; off >>= 1) {
            dot += __shfl_xor(dot, off, 64);
            nx  += __shfl_xor(nx,  off, 64);
            ndn += __shfl_xor(ndn, off, 64);
        }
        if (lane == 0 && node < NN)
            raw2[node] = dot / ((sqrtf(nx) + 1e-6f) * (sqrtf(ndn) + 1e-6f));
    }
    if (lane < 16) {
        int node = blockBase + wave * 16 + lane;
        if (node < NN) raw0[node] = logf(deg_c[node] + 1.0f);
    }
}

// ============ K5: block-level f64 partial sums (sum, sumsq) x3 ============
__global__ __launch_bounds__(256) void k_reduce(
    const float* __restrict__ r0, const float* __restrict__ r1,
    const float* __restrict__ r2, double* __restrict__ partials)
{
    __shared__ double sd[256];
    double s[6] = {0,0,0,0,0,0};
    for (int n = blockIdx.x * 256 + threadIdx.x; n < NN; n += 256 * NRED) {
        double v0 = r0[n], v1 = r1[n], v2 = r2[n];
        s[0] += v0; s[1] += v0*v0;
        s[2] += v1; s[3] += v1*v1;
        s[4] += v2; s[5] += v2*v2;
    }
    for (int q = 0; q < 6; q++) {
        sd[threadIdx.x] = s[q];
        __syncthreads();
        for (int off = 128; off; off >>= 1) {
            if (threadIdx.x < off) sd[threadIdx.x] += sd[threadIdx.x + off];
            __syncthreads();
        }
        if (threadIdx.x == 0) partials[blockIdx.x * 6 + q] = sd[0];
        __syncthreads();
    }
}

// ============ K6: final stats -> mean, 1/(std+eps) per view ============
__global__ __launch_bounds__(256) void k_stats(const double* __restrict__ partials,
                                               float* __restrict__ stats)
{
    __shared__ double sd[256];
    __shared__ double sums[6];
    for (int q = 0; q < 6; q++) {
        sd[threadIdx.x] = (threadIdx.x < NRED) ? partials[threadIdx.x * 6 + q] : 0.0;
        __syncthreads();
        for (int off = 128; off; off >>= 1) {
            if (threadIdx.x < off) sd[threadIdx.x] += sd[threadIdx.x + off];
            __syncthreads();
        }
        if (threadIdx.x == 0) sums[q] = sd[0];
        __syncthreads();
    }
    if (threadIdx.x == 0) {
        for (int i = 0; i < 3; i++) {
            double sum = sums[2*i], sq = sums[2*i+1];
            double mean = sum / NN;
            double var = (sq - sum * sum / NN) / (NN - 1);
            double sdv = sqrt(var > 0 ? var : 0);
            stats[2*i]   = (float)mean;
            stats[2*i+1] = (float)(1.0 / (sdv + 1e-6));
        }
    }
}

// ============ K7: score = sigmoid(z @ vw) ============
__global__ __launch_bounds__(256) void k_score(
    const float* __restrict__ r0, const float* __restrict__ r1,
    const float* __restrict__ r2, const float* __restrict__ stats,
    const float* __restrict__ vw, float* __restrict__ score)
{
    int n = blockIdx.x * 256 + threadIdx.x;
    if (n >= NN) return;
    float z0 = (r0[n] - stats[0]) * stats[1];
    float z1 = (r1[n] - stats[2]) * stats[3];
    float z2 = (r2[n] - stats[4]) * stats[5];
    float r = z0 * vw[0] + z1 * vw[1] + z2 * vw[2];
    score[n] = 1.f / (1.f + expf(-r));
}

// ============ K8: per-graph top-K via bitonic sort of 2048 keys ============
__global__ __launch_bounds__(1024) void k_topk(
    const float* __restrict__ score, int* __restrict__ keep,
    int* __restrict__ new_id, float* __restrict__ obatch)
{
    __shared__ unsigned long long keys[2048];
    int b = blockIdx.x;
    unsigned t = threadIdx.x;
    for (unsigned i = t; i < 2048; i += 1024) {
        unsigned long long kk = 0ull;
        if (i < NPG) {
            float sc = score[b * NPG + i];
            kk = ((unsigned long long)__float_as_uint(sc) << 32)
               | (unsigned long long)(0xFFFFFFFFu - i);
        }
        keys[i] = kk;
    }
    __syncthreads();
    for (unsigned k = 2; k <= 2048; k <<= 1) {
        for (unsigned j = k >> 1; j > 0; j >>= 1) {
            unsigned i = ((t & ~(j - 1)) << 1) | (t & (j - 1));
            unsigned p = i | j;
            unsigned long long a = keys[i], c = keys[p];
            bool up = ((i & k) == 0);
            if ((a < c) == up) { keys[i] = c; keys[p] = a; }
            __syncthreads();
        }
    }
    if (t < KK) {
        unsigned long long kk = keys[t];
        unsigned li = 0xFFFFFFFFu - (unsigned)(kk & 0xFFFFFFFFu);
        int node = b * NPG + (int)li;
        int j = b * KK + (int)t;
        keep[j] = node;
        new_id[node] = j;
        obatch[j] = (float)b;
    }
}

// ============ K9: out_x = x[keep] * score[keep] ============
__global__ __launch_bounds__(128) void k_outx(
    const float* __restrict__ x, const float* __restrict__ score,
    const int* __restrict__ keep, float* __restrict__ out_x)
{
    int j = blockIdx.x;
    int node = keep[j];
    float s = score[node];
    out_x[(size_t)j * DD + threadIdx.x] = x[(size_t)node * DD + threadIdx.x] * s;
}

// ============ K10a: edge mask + new edge_index ============
__global__ __launch_bounds__(256) void k_edges(
    const int* __restrict__ src, const int* __restrict__ dst,
    const int* __restrict__ new_id, float* __restrict__ oei,
    float* __restrict__ emask)
{
    int e = blockIdx.x * 256 + threadIdx.x;
    if (e >= EE) return;
    int ns = new_id[src[e]], nd = new_id[dst[e]];
    bool m = (ns >= 0) && (nd >= 0);
    oei[e]      = m ? (float)ns : 0.f;
    oei[EE + e] = m ? (float)nd : 0.f;
    emask[e]    = m ? 1.f : 0.f;
}

// ============ K10b: masked edge_attr copy (float4) ============
__global__ __launch_bounds__(256) void k_attr(
    const float* __restrict__ edge_attr, const float* __restrict__ emask,
    float* __restrict__ oea)
{
    int idx = blockIdx.x * 256 + threadIdx.x;
    if (idx >= EE * 4) return;
    int e = idx >> 2;
    float m = emask[e];
    float4 v = ((const float4*)edge_attr)[idx];
    float4 o; o.x = v.x*m; o.y = v.y*m; o.z = v.z*m; o.w = v.w*m;
    ((float4*)oea)[idx] = o;
}

extern "C" void kernel_launch(void* const* d_in, const int* in_sizes, int n_in,
                              void* d_out, int out_size, void* d_ws, size_t ws_size,
                              hipStream_t stream) {
    const float* x         = (const float*)d_in[0];
    const int*   edge_idx  = (const int*)d_in[1];
    const float* edge_attr = (const float*)d_in[2];
    const float* W1  = (const float*)d_in[4];
    const float* b1  = (const float*)d_in[5];
    const float* W2  = (const float*)d_in[6];
    const float* b2  = (const float*)d_in[7];
    const float* We1 = (const float*)d_in[8];
    const float* be1 = (const float*)d_in[9];
    const float* We2 = (const float*)d_in[10];
    const float* be2 = (const float*)d_in[11];
    const float* vw  = (const float*)d_in[12];

    const int* src = edge_idx;
    const int* dst = edge_idx + EE;

    float* out    = (float*)d_out;
    float* out_x  = out;
    float* oei    = out + OFF_OEI;
    float* oea    = out + OFF_OEA;
    float* obatch = out + OFF_OBATCH;
    float* emask  = out + OFF_EMASK;

    // scratch inside d_out (dead before any output writer runs)
    float* x_diff    = out;                       // 12.8M floats
    int*   csr_dst   = (int*)(out + 12800000);    // 600k
    float* csr_w     = out + 13400000;            // 600k
    int*   rowstart  = (int*)(out + 14000000);    // 100k
    int*   cur       = (int*)(out + 14100000);    // 100k
    int*   scanned   = (int*)(out + 14200000);    // 100k
    int*   blocksums = (int*)(out + 14300000);    // 256

    // workspace layout (floats) — ~5.9 MB total
    float* ws     = (float*)d_ws;
    float* ew     = ws;                     // 600000
    float* deg_w  = ws + 600000;            // 100000
    float* deg_c  = ws + 700000;            // 100000 (adjacent to deg_w)
    float* dis    = ws + 800000;            // 100000
    float* score  = ws + 900000;            // 100000
    float* raw0   = ws + 1000000;           // 100000
    float* raw1   = ws + 1100000;           // 100000
    float* raw2   = ws + 1200000;           // 100000
    int*   keep   = (int*)(ws + 1300000);   // 50000
    int*   new_id = (int*)(ws + 1350000);   // 100000
    double* partials = (double*)(ws + 1450000); // NRED*6 doubles
    float* stats  = ws + 1450000 + 2 * 6 * NRED; // 6 floats

    hipMemsetAsync(deg_w, 0, 2 * NN * sizeof(float), stream); // deg_w + deg_c
    hipMemsetAsync(new_id, 0xFF, NN * sizeof(int), stream);   // -1

    k_edge_mlp<<<(EE + 255) / 256, 256, 0, stream>>>(edge_attr, src, We1, be1, We2, be2,
                                                     ew, deg_w, deg_c);
    k_dis<<<(NN + 255) / 256, 256, 0, stream>>>(deg_w, dis);
    // CSR build
    k_scan_block<<<SCAN_NB, 1024, 0, stream>>>(deg_c, scanned, blocksums);
    k_scan_top<<<1, 128, 0, stream>>>(blocksums);
    k_cursor<<<(NN + 255) / 256, 256, 0, stream>>>(scanned, blocksums, rowstart, cur);
    k_scatter<<<(EE + 255) / 256, 256, 0, stream>>>(src, dst, ew, dis, cur, csr_dst, csr_w);
    // gather diffusion (no atomics)
    k_gather<<<(NN * 64 + 255) / 256, 256, 0, stream>>>(rowstart, deg_c, csr_dst, csr_w,
                                                        x, x_diff);
    k_node<<<(NN + 63) / 64, 256, 0, stream>>>(x, x_diff, W1, b1, W2, b2, deg_c,
                                               raw0, raw1, raw2);
    k_reduce<<<NRED, 256, 0, stream>>>(raw0, raw1, raw2, partials);
    k_stats<<<1, 256, 0, stream>>>(partials, stats);
    k_score<<<(NN + 255) / 256, 256, 0, stream>>>(raw0, raw1, raw2, stats, vw, score);
    k_topk<<<BB, 1024, 0, stream>>>(score, keep, new_id, obatch);
    k_outx<<<NKEEP, 128, 0, stream>>>(x, score, keep, out_x);
    k_edges<<<(EE + 255) / 256, 256, 0, stream>>>(src, dst, new_id, oei, emask);
    k_attr<<<(EE * 4 + 255) / 256, 256, 0, stream>>>(edge_attr, emask, oea);
}

// Round 4
// 452.592 us; speedup vs baseline: 1.1324x; 1.1324x over previous
//
#include <hip/hip_runtime.h>
#include <math.h>

// ---- problem constants (match reference) ----
#define NN   100000   // nodes
#define DD   128      // in_channels
#define EE   600000   // edges
#define EAD  16       // edge_attr dim
#define BB   50       // graphs
#define NPG  2000     // nodes per graph
#define KK   1000     // kept per graph
#define NKEEP (BB*KK) // 50000

// output layout (floats, concatenated in return order)
#define OFF_OEI    6400000
#define OFF_OEA    7600000
#define OFF_OBATCH 17200000
#define OFF_EMASK  17250000

#define NRED 240  // reduction blocks
#define SCAN_NB 98 // ceil(100000/1024)

// ============ K1: edge MLP -> ew, deg_w, deg_c ============
// We1^T staged in LDS (broadcast reads), 4 edges per thread.
#define EPB 1024
__global__ __launch_bounds__(256) void k_edge_mlp(
    const float* __restrict__ edge_attr, const int* __restrict__ src,
    const float* __restrict__ We1, const float* __restrict__ be1,
    const float* __restrict__ We2, const float* __restrict__ be2,
    float* __restrict__ ew, float* __restrict__ deg_w, float* __restrict__ deg_c)
{
    __shared__ float wt[2048];  // wt[j*16+k] = We1[k][j]
    __shared__ float b1s[128];
    __shared__ float w2s[128];
    for (int idx = threadIdx.x; idx < 2048; idx += 256) {
        int j = idx >> 4, k = idx & 15;
        wt[idx] = We1[k * DD + j];
    }
    if (threadIdx.x < 128) {
        b1s[threadIdx.x] = be1[threadIdx.x];
        w2s[threadIdx.x] = We2[threadIdx.x];
    }
    __syncthreads();

    int e0 = blockIdx.x * EPB + threadIdx.x;
    float ea[4][16];
    #pragma unroll
    for (int i = 0; i < 4; i++) {
        int e = e0 + 256 * i; if (e >= EE) e = EE - 1;
        const float4* ap = (const float4*)(edge_attr + (size_t)e * EAD);
        float4 a0 = ap[0], a1 = ap[1], a2 = ap[2], a3 = ap[3];
        ea[i][0]=a0.x; ea[i][1]=a0.y; ea[i][2]=a0.z; ea[i][3]=a0.w;
        ea[i][4]=a1.x; ea[i][5]=a1.y; ea[i][6]=a1.z; ea[i][7]=a1.w;
        ea[i][8]=a2.x; ea[i][9]=a2.y; ea[i][10]=a2.z; ea[i][11]=a2.w;
        ea[i][12]=a3.x; ea[i][13]=a3.y; ea[i][14]=a3.z; ea[i][15]=a3.w;
    }
    float acc[4] = {0.f, 0.f, 0.f, 0.f};
    for (int j = 0; j < DD; j++) {
        float4 w0 = *(const float4*)(wt + j*16);
        float4 w1 = *(const float4*)(wt + j*16 + 4);
        float4 w2 = *(const float4*)(wt + j*16 + 8);
        float4 w3 = *(const float4*)(wt + j*16 + 12);
        float bj = b1s[j], w2j = w2s[j];
        #pragma unroll
        for (int i = 0; i < 4; i++) {
            float h = bj;
            h += ea[i][0]*w0.x;  h += ea[i][1]*w0.y;
            h += ea[i][2]*w0.z;  h += ea[i][3]*w0.w;
            h += ea[i][4]*w1.x;  h += ea[i][5]*w1.y;
            h += ea[i][6]*w1.z;  h += ea[i][7]*w1.w;
            h += ea[i][8]*w2.x;  h += ea[i][9]*w2.y;
            h += ea[i][10]*w2.z; h += ea[i][11]*w2.w;
            h += ea[i][12]*w3.x; h += ea[i][13]*w3.y;
            h += ea[i][14]*w3.z; h += ea[i][15]*w3.w;
            acc[i] += fmaxf(h, 0.f) * w2j;
        }
    }
    float bias2 = be2[0];
    #pragma unroll
    for (int i = 0; i < 4; i++) {
        int e = e0 + 256 * i;
        if (e < EE) {
            float a = acc[i] + bias2;
            float sp = fmaxf(a, 0.f) + log1pf(expf(-fabsf(a)));
            float w = sp + 1e-6f;
            ew[e] = w;
            int s = src[e];
            atomicAdd(&deg_w[s], w);
            atomicAdd(&deg_c[s], 1.0f);
        }
    }
}

// ============ K2: dis = deg_w^-0.5 ============
__global__ __launch_bounds__(256) void k_dis(const float* __restrict__ deg_w,
                                             float* __restrict__ dis)
{
    int n = blockIdx.x * 256 + threadIdx.x;
    if (n >= NN) return;
    float d = deg_w[n];
    dis[n] = d > 0.f ? 1.f / sqrtf(d) : 0.f;
}

// ============ K3a: per-1024-block exclusive scan of degree counts ============
__global__ __launch_bounds__(1024) void k_scan_block(
    const float* __restrict__ deg_c, int* __restrict__ scanned,
    int* __restrict__ blocksums)
{
    __shared__ int s[1024];
    int i = blockIdx.x * 1024 + threadIdx.x;
    int c = (i < NN) ? (int)deg_c[i] : 0;
    s[threadIdx.x] = c;
    __syncthreads();
    for (int off = 1; off < 1024; off <<= 1) {
        int v = (threadIdx.x >= off) ? s[threadIdx.x - off] : 0;
        __syncthreads();
        s[threadIdx.x] += v;
        __syncthreads();
    }
    if (i < NN) scanned[i] = s[threadIdx.x] - c; // exclusive
    if (threadIdx.x == 1023) blocksums[blockIdx.x] = s[1023];
}

// ============ K3b: scan the block sums (one block) ============
__global__ __launch_bounds__(128) void k_scan_top(int* __restrict__ blocksums)
{
    __shared__ int s[128];
    int c = (threadIdx.x < SCAN_NB) ? blocksums[threadIdx.x] : 0;
    s[threadIdx.x] = c;
    __syncthreads();
    for (int off = 1; off < 128; off <<= 1) {
        int v = (threadIdx.x >= off) ? s[threadIdx.x - off] : 0;
        __syncthreads();
        s[threadIdx.x] += v;
        __syncthreads();
    }
    if (threadIdx.x < SCAN_NB) blocksums[threadIdx.x] = s[threadIdx.x] - c; // exclusive
}

// ============ K3c: rowstart / cursor init ============
__global__ __launch_bounds__(256) void k_cursor(
    const int* __restrict__ scanned, const int* __restrict__ blocksums,
    int* __restrict__ rowstart, int* __restrict__ cur)
{
    int n = blockIdx.x * 256 + threadIdx.x;
    if (n >= NN) return;
    int st = scanned[n] + blocksums[n >> 10];
    rowstart[n] = st;
    cur[n] = st;
}

// ============ K3d: scatter edges into CSR buckets (dst + norm) ============
__global__ __launch_bounds__(256) void k_scatter(
    const int* __restrict__ src, const int* __restrict__ dst,
    const float* __restrict__ ew, const float* __restrict__ dis,
    int* __restrict__ cur, int* __restrict__ csr_dst, float* __restrict__ csr_w)
{
    int e = blockIdx.x * 256 + threadIdx.x;
    if (e >= EE) return;
    int s = src[e], d = dst[e];
    float w = dis[s] * ew[e] * dis[d];
    int pos = atomicAdd(&cur[s], 1);
    csr_dst[pos] = d;
    csr_w[pos] = w;
}

// ============ K3e: fused diffusion gather + cosine + log-degree ============
// One wave per node. csr slice loaded once into lanes, indices broadcast via
// shfl -> 4 independent x-row loads in flight. x_diff never materialized.
__global__ __launch_bounds__(256) void k_gather_cos(
    const int* __restrict__ rowstart, const float* __restrict__ deg_c,
    const int* __restrict__ csr_dst, const float* __restrict__ csr_w,
    const float* __restrict__ x, float* __restrict__ raw0, float* __restrict__ raw2)
{
    int node = (blockIdx.x * 256 + threadIdx.x) >> 6;
    int lane = threadIdx.x & 63;
    if (node >= NN) return;
    int start = rowstart[node];
    int deg = (int)deg_c[node];
    const float2* xp = (const float2*)x;
    float2 xn = xp[(size_t)node * 64 + lane];
    float2 acc = {0.f, 0.f};
    for (int base = 0; base < deg; base += 64) {
        int rem = deg - base; if (rem > 64) rem = 64;
        int md = 0; float mw = 0.f;
        if (lane < rem) {
            md = csr_dst[start + base + lane];
            mw = csr_w[start + base + lane];
        }
        int e = 0;
        for (; e + 4 <= rem; e += 4) {
            int d0 = __shfl(md, e, 64),   d1 = __shfl(md, e+1, 64);
            int d2 = __shfl(md, e+2, 64), d3 = __shfl(md, e+3, 64);
            float w0 = __shfl(mw, e, 64),   w1 = __shfl(mw, e+1, 64);
            float w2 = __shfl(mw, e+2, 64), w3 = __shfl(mw, e+3, 64);
            float2 v0 = xp[(size_t)d0 * 64 + lane];
            float2 v1 = xp[(size_t)d1 * 64 + lane];
            float2 v2 = xp[(size_t)d2 * 64 + lane];
            float2 v3 = xp[(size_t)d3 * 64 + lane];
            acc.x += w0 * v0.x; acc.y += w0 * v0.y;
            acc.x += w1 * v1.x; acc.y += w1 * v1.y;
            acc.x += w2 * v2.x; acc.y += w2 * v2.y;
            acc.x += w3 * v3.x; acc.y += w3 * v3.y;
        }
        for (; e < rem; e++) {
            int d = __shfl(md, e, 64);
            float w = __shfl(mw, e, 64);
            float2 v = xp[(size_t)d * 64 + lane];
            acc.x += w * v.x; acc.y += w * v.y;
        }
    }
    float dot = xn.x * acc.x + xn.y * acc.y;
    float nx  = xn.x * xn.x + xn.y * xn.y;
    float nd  = acc.x * acc.x + acc.y * acc.y;
    #pragma unroll
    for (int off = 32; off; off >>= 1) {
        dot += __shfl_xor(dot, off, 64);
        nx  += __shfl_xor(nx,  off, 64);
        nd  += __shfl_xor(nd,  off, 64);
    }
    if (lane == 0) {
        raw2[node] = dot / ((sqrtf(nx) + 1e-6f) * (sqrtf(nd) + 1e-6f));
        raw0[node] = logf((float)deg + 1.0f);
    }
}

// ============ K4: per-node feat MLP (register-blocked GEMM) ============
#define XSTR 132  // x row stride in LDS: %4==0 (float4), %32==4 (2-way conflicts)
__global__ __launch_bounds__(256) void k_node(
    const float* __restrict__ x,
    const float* __restrict__ W1, const float* __restrict__ b1,
    const float* __restrict__ W2, const float* __restrict__ b2,
    float* __restrict__ raw1)
{
    __shared__ float xs[64 * XSTR]; // 33.8 KB
    int wave = threadIdx.x >> 6, lane = threadIdx.x & 63;
    int ng = lane >> 4, jg = lane & 15;
    int blockBase = blockIdx.x * 64;

    #pragma unroll
    for (int it = 0; it < 8; it++) {
        int s = threadIdx.x + 256 * it;
        int row = s >> 5, c4 = s & 31;
        int gn = blockBase + row; if (gn >= NN) gn = NN - 1;
        *(float4*)(xs + row * XSTR + c4 * 4) =
            *(const float4*)(x + (size_t)gn * DD + c4 * 4);
    }
    __syncthreads();

    const float* xw = xs + (wave * 16 + ng * 4) * XSTR;
    int j0 = jg * 8;
    float acc[4][8];
    #pragma unroll
    for (int i = 0; i < 4; i++)
        #pragma unroll
        for (int jj = 0; jj < 8; jj++) acc[i][jj] = 0.f;

    for (int k = 0; k < DD; k += 4) {
        float4 xv[4];
        #pragma unroll
        for (int i = 0; i < 4; i++) xv[i] = *(const float4*)(xw + i * XSTR + k);
        float4 wv[4][2];
        #pragma unroll
        for (int kk = 0; kk < 4; kk++) {
            wv[kk][0] = *(const float4*)(W1 + (k + kk) * DD + j0);
            wv[kk][1] = *(const float4*)(W1 + (k + kk) * DD + j0 + 4);
        }
        #pragma unroll
        for (int i = 0; i < 4; i++) {
            const float xe[4] = {xv[i].x, xv[i].y, xv[i].z, xv[i].w};
            #pragma unroll
            for (int kk = 0; kk < 4; kk++) {
                acc[i][0] += xe[kk] * wv[kk][0].x;
                acc[i][1] += xe[kk] * wv[kk][0].y;
                acc[i][2] += xe[kk] * wv[kk][0].z;
                acc[i][3] += xe[kk] * wv[kk][0].w;
                acc[i][4] += xe[kk] * wv[kk][1].x;
                acc[i][5] += xe[kk] * wv[kk][1].y;
                acc[i][6] += xe[kk] * wv[kk][1].z;
                acc[i][7] += xe[kk] * wv[kk][1].w;
            }
        }
    }

    float4 b1a = *(const float4*)(b1 + j0), b1b = *(const float4*)(b1 + j0 + 4);
    float4 w2a = *(const float4*)(W2 + j0), w2b = *(const float4*)(W2 + j0 + 4);
    const float b1v[8] = {b1a.x,b1a.y,b1a.z,b1a.w, b1b.x,b1b.y,b1b.z,b1b.w};
    const float w2v[8] = {w2a.x,w2a.y,w2a.z,w2a.w, w2b.x,w2b.y,w2b.z,w2b.w};
    float bias2 = b2[0];
    #pragma unroll
    for (int i = 0; i < 4; i++) {
        float p = 0.f;
        #pragma unroll
        for (int jj = 0; jj < 8; jj++)
            p += fmaxf(acc[i][jj] + b1v[jj], 0.f) * w2v[jj];
        p += __shfl_xor(p, 1, 64);
        p += __shfl_xor(p, 2, 64);
        p += __shfl_xor(p, 4, 64);
        p += __shfl_xor(p, 8, 64);
        int node = blockBase + wave * 16 + ng * 4 + i;
        if (jg == 0 && node < NN) raw1[node] = p + bias2;
    }
}

// ============ K5: block-level f64 partial sums (sum, sumsq) x3 ============
__global__ __launch_bounds__(256) void k_reduce(
    const float* __restrict__ r0, const float* __restrict__ r1,
    const float* __restrict__ r2, double* __restrict__ partials)
{
    __shared__ double sd[256];
    double s[6] = {0,0,0,0,0,0};
    for (int n = blockIdx.x * 256 + threadIdx.x; n < NN; n += 256 * NRED) {
        double v0 = r0[n], v1 = r1[n], v2 = r2[n];
        s[0] += v0; s[1] += v0*v0;
        s[2] += v1; s[3] += v1*v1;
        s[4] += v2; s[5] += v2*v2;
    }
    for (int q = 0; q < 6; q++) {
        sd[threadIdx.x] = s[q];
        __syncthreads();
        for (int off = 128; off; off >>= 1) {
            if (threadIdx.x < off) sd[threadIdx.x] += sd[threadIdx.x + off];
            __syncthreads();
        }
        if (threadIdx.x == 0) partials[blockIdx.x * 6 + q] = sd[0];
        __syncthreads();
    }
}

// ============ K6: final stats -> mean, 1/(std+eps) per view ============
__global__ __launch_bounds__(256) void k_stats(const double* __restrict__ partials,
                                               float* __restrict__ stats)
{
    __shared__ double sd[256];
    __shared__ double sums[6];
    for (int q = 0; q < 6; q++) {
        sd[threadIdx.x] = (threadIdx.x < NRED) ? partials[threadIdx.x * 6 + q] : 0.0;
        __syncthreads();
        for (int off = 128; off; off >>= 1) {
            if (threadIdx.x < off) sd[threadIdx.x] += sd[threadIdx.x + off];
            __syncthreads();
        }
        if (threadIdx.x == 0) sums[q] = sd[0];
        __syncthreads();
    }
    if (threadIdx.x == 0) {
        for (int i = 0; i < 3; i++) {
            double sum = sums[2*i], sq = sums[2*i+1];
            double mean = sum / NN;
            double var = (sq - sum * sum / NN) / (NN - 1);
            double sdv = sqrt(var > 0 ? var : 0);
            stats[2*i]   = (float)mean;
            stats[2*i+1] = (float)(1.0 / (sdv + 1e-6));
        }
    }
}

// ============ K7: score = sigmoid(z @ vw) ============
__global__ __launch_bounds__(256) void k_score(
    const float* __restrict__ r0, const float* __restrict__ r1,
    const float* __restrict__ r2, const float* __restrict__ stats,
    const float* __restrict__ vw, float* __restrict__ score)
{
    int n = blockIdx.x * 256 + threadIdx.x;
    if (n >= NN) return;
    float z0 = (r0[n] - stats[0]) * stats[1];
    float z1 = (r1[n] - stats[2]) * stats[3];
    float z2 = (r2[n] - stats[4]) * stats[5];
    float r = z0 * vw[0] + z1 * vw[1] + z2 * vw[2];
    score[n] = 1.f / (1.f + expf(-r));
}

// ============ K8: per-graph top-K via bitonic sort of 2048 keys ============
__global__ __launch_bounds__(1024) void k_topk(
    const float* __restrict__ score, int* __restrict__ keep,
    int* __restrict__ new_id, float* __restrict__ obatch)
{
    __shared__ unsigned long long keys[2048];
    int b = blockIdx.x;
    unsigned t = threadIdx.x;
    for (unsigned i = t; i < 2048; i += 1024) {
        unsigned long long kk = 0ull;
        if (i < NPG) {
            float sc = score[b * NPG + i];
            kk = ((unsigned long long)__float_as_uint(sc) << 32)
               | (unsigned long long)(0xFFFFFFFFu - i);
        }
        keys[i] = kk;
    }
    __syncthreads();
    for (unsigned k = 2; k <= 2048; k <<= 1) {
        for (unsigned j = k >> 1; j > 0; j >>= 1) {
            unsigned i = ((t & ~(j - 1)) << 1) | (t & (j - 1));
            unsigned p = i | j;
            unsigned long long a = keys[i], c = keys[p];
            bool up = ((i & k) == 0);
            if ((a < c) == up) { keys[i] = c; keys[p] = a; }
            __syncthreads();
        }
    }
    if (t < KK) {
        unsigned long long kk = keys[t];
        unsigned li = 0xFFFFFFFFu - (unsigned)(kk & 0xFFFFFFFFu);
        int node = b * NPG + (int)li;
        int j = b * KK + (int)t;
        keep[j] = node;
        new_id[node] = j;
        obatch[j] = (float)b;
    }
}

// ============ K9: out_x = x[keep] * score[keep] ============
__global__ __launch_bounds__(128) void k_outx(
    const float* __restrict__ x, const float* __restrict__ score,
    const int* __restrict__ keep, float* __restrict__ out_x)
{
    int j = blockIdx.x;
    int node = keep[j];
    float s = score[node];
    out_x[(size_t)j * DD + threadIdx.x] = x[(size_t)node * DD + threadIdx.x] * s;
}

// ============ K10a: edge mask + new edge_index ============
__global__ __launch_bounds__(256) void k_edges(
    const int* __restrict__ src, const int* __restrict__ dst,
    const int* __restrict__ new_id, float* __restrict__ oei,
    float* __restrict__ emask)
{
    int e = blockIdx.x * 256 + threadIdx.x;
    if (e >= EE) return;
    int ns = new_id[src[e]], nd = new_id[dst[e]];
    bool m = (ns >= 0) && (nd >= 0);
    oei[e]      = m ? (float)ns : 0.f;
    oei[EE + e] = m ? (float)nd : 0.f;
    emask[e]    = m ? 1.f : 0.f;
}

// ============ K10b: masked edge_attr copy (float4) ============
__global__ __launch_bounds__(256) void k_attr(
    const float* __restrict__ edge_attr, const float* __restrict__ emask,
    float* __restrict__ oea)
{
    int idx = blockIdx.x * 256 + threadIdx.x;
    if (idx >= EE * 4) return;
    int e = idx >> 2;
    float m = emask[e];
    float4 v = ((const float4*)edge_attr)[idx];
    float4 o; o.x = v.x*m; o.y = v.y*m; o.z = v.z*m; o.w = v.w*m;
    ((float4*)oea)[idx] = o;
}

extern "C" void kernel_launch(void* const* d_in, const int* in_sizes, int n_in,
                              void* d_out, int out_size, void* d_ws, size_t ws_size,
                              hipStream_t stream) {
    const float* x         = (const float*)d_in[0];
    const int*   edge_idx  = (const int*)d_in[1];
    const float* edge_attr = (const float*)d_in[2];
    const float* W1  = (const float*)d_in[4];
    const float* b1  = (const float*)d_in[5];
    const float* W2  = (const float*)d_in[6];
    const float* b2  = (const float*)d_in[7];
    const float* We1 = (const float*)d_in[8];
    const float* be1 = (const float*)d_in[9];
    const float* We2 = (const float*)d_in[10];
    const float* be2 = (const float*)d_in[11];
    const float* vw  = (const float*)d_in[12];

    const int* src = edge_idx;
    const int* dst = edge_idx + EE;

    float* out    = (float*)d_out;
    float* out_x  = out;
    float* oei    = out + OFF_OEI;
    float* oea    = out + OFF_OEA;
    float* obatch = out + OFF_OBATCH;
    float* emask  = out + OFF_EMASK;

    // scratch inside d_out (dead before any output writer runs)
    int*   csr_dst   = (int*)(out + 12800000);    // 600k
    float* csr_w     = out + 13400000;            // 600k
    int*   rowstart  = (int*)(out + 14000000);    // 100k
    int*   cur       = (int*)(out + 14100000);    // 100k
    int*   scanned   = (int*)(out + 14200000);    // 100k
    int*   blocksums = (int*)(out + 14300000);    // 256

    // workspace layout (floats) — ~5.9 MB total
    float* ws     = (float*)d_ws;
    float* ew     = ws;                     // 600000
    float* deg_w  = ws + 600000;            // 100000
    float* deg_c  = ws + 700000;            // 100000 (adjacent to deg_w)
    float* dis    = ws + 800000;            // 100000
    float* score  = ws + 900000;            // 100000
    float* raw0   = ws + 1000000;           // 100000
    float* raw1   = ws + 1100000;           // 100000
    float* raw2   = ws + 1200000;           // 100000
    int*   keep   = (int*)(ws + 1300000);   // 50000
    int*   new_id = (int*)(ws + 1350000);   // 100000
    double* partials = (double*)(ws + 1450000); // NRED*6 doubles
    float* stats  = ws + 1450000 + 2 * 6 * NRED; // 6 floats

    hipMemsetAsync(deg_w, 0, 2 * NN * sizeof(float), stream); // deg_w + deg_c
    hipMemsetAsync(new_id, 0xFF, NN * sizeof(int), stream);   // -1

    k_edge_mlp<<<(EE + EPB - 1) / EPB, 256, 0, stream>>>(edge_attr, src, We1, be1,
                                                         We2, be2, ew, deg_w, deg_c);
    k_dis<<<(NN + 255) / 256, 256, 0, stream>>>(deg_w, dis);
    // CSR build
    k_scan_block<<<SCAN_NB, 1024, 0, stream>>>(deg_c, scanned, blocksums);
    k_scan_top<<<1, 128, 0, stream>>>(blocksums);
    k_cursor<<<(NN + 255) / 256, 256, 0, stream>>>(scanned, blocksums, rowstart, cur);
    k_scatter<<<(EE + 255) / 256, 256, 0, stream>>>(src, dst, ew, dis, cur, csr_dst, csr_w);
    // fused diffusion gather + cosine + log-degree (x_diff never materialized)
    k_gather_cos<<<(NN * 64 + 255) / 256, 256, 0, stream>>>(rowstart, deg_c, csr_dst,
                                                            csr_w, x, raw0, raw2);
    k_node<<<(NN + 63) / 64, 256, 0, stream>>>(x, W1, b1, W2, b2, raw1);
    k_reduce<<<NRED, 256, 0, stream>>>(raw0, raw1, raw2, partials);
    k_stats<<<1, 256, 0, stream>>>(partials, stats);
    k_score<<<(NN + 255) / 256, 256, 0, stream>>>(raw0, raw1, raw2, stats, vw, score);
    k_topk<<<BB, 1024, 0, stream>>>(score, keep, new_id, obatch);
    k_outx<<<NKEEP, 128, 0, stream>>>(x, score, keep, out_x);
    k_edges<<<(EE + 255) / 256, 256, 0, stream>>>(src, dst, new_id, oei, emask);
    k_attr<<<(EE * 4 + 255) / 256, 256, 0, stream>>>(edge_attr, emask, oea);
}

// Round 5
// 435.837 us; speedup vs baseline: 1.1760x; 1.0384x over previous
//
#include <hip/hip_runtime.h>
#include <math.h>

// ---- problem constants (match reference) ----
#define NN   100000   // nodes
#define DD   128      // in_channels
#define EE   600000   // edges
#define EAD  16       // edge_attr dim
#define BB   50       // graphs
#define NPG  2000     // nodes per graph
#define KK   1000     // kept per graph
#define NKEEP (BB*KK) // 50000

// output layout (floats, concatenated in return order)
#define OFF_OEI    6400000
#define OFF_OEA    7600000
#define OFF_OBATCH 17200000
#define OFF_EMASK  17250000

#define NRED 240  // reduction blocks
#define SCAN_NB 98 // ceil(100000/1024)

// ============ K1: edge MLP -> ew, deg_w, deg_c ============
// j-split across lanes: jg = lane&31 owns 4 j-columns (weights in VGPRs,
// loaded once); es = lane>>5 -> 2 edges in flight per wave. edge_attr tiles
// staged in LDS. Grid-stride over 256-edge tiles for occupancy.
#define ETILES ((EE + 255) / 256)  // 2344
#define EMLP_GRID 1024
__global__ __launch_bounds__(256) void k_edge_mlp(
    const float* __restrict__ edge_attr, const int* __restrict__ src,
    const float* __restrict__ We1, const float* __restrict__ be1,
    const float* __restrict__ We2, const float* __restrict__ be2,
    float* __restrict__ ew, float* __restrict__ deg_w, float* __restrict__ deg_c)
{
    __shared__ float ea[256 * 16];   // 16 KB edge-attr tile
    __shared__ float ptile[256];
    int lane = threadIdx.x & 63, wv = threadIdx.x >> 6;
    int jg = lane & 31, es = lane >> 5;
    int j0 = jg * 4;

    // per-lane weights: wr[j*16+k] = We1[k][j0+j]  (64 VGPRs, L2-hot)
    float wr[64];
    #pragma unroll
    for (int j = 0; j < 4; j++)
        #pragma unroll
        for (int k = 0; k < 16; k++)
            wr[j * 16 + k] = We1[k * DD + j0 + j];
    float b1r[4], w2r[4];
    #pragma unroll
    for (int j = 0; j < 4; j++) { b1r[j] = be1[j0 + j]; w2r[j] = We2[j0 + j]; }
    float bias2 = be2[0];

    for (int tile = blockIdx.x; tile < ETILES; tile += EMLP_GRID) {
        int ebase = tile * 256;
        // cooperative coalesced load: 256 edges x 16 floats = 1024 float4
        #pragma unroll
        for (int it = 0; it < 4; it++) {
            int idx = threadIdx.x + 256 * it;          // float4 slot
            long long gidx = (long long)ebase * 4 + idx; // global float4 idx
            long long maxg = (long long)EE * 4;
            if (gidx >= maxg) gidx = maxg - 1;
            ((float4*)ea)[idx] = ((const float4*)edge_attr)[gidx];
        }
        __syncthreads();

        // each wave: 64 tile-edges, 2 at a time (es slots)
        #pragma unroll 2
        for (int it = 0; it < 32; it++) {
            int le = wv * 64 + it * 2 + es;
            const float* a = ea + le * 16;
            float4 a0 = *(const float4*)(a);
            float4 a1 = *(const float4*)(a + 4);
            float4 a2 = *(const float4*)(a + 8);
            float4 a3 = *(const float4*)(a + 12);
            const float av[16] = {a0.x,a0.y,a0.z,a0.w, a1.x,a1.y,a1.z,a1.w,
                                  a2.x,a2.y,a2.z,a2.w, a3.x,a3.y,a3.z,a3.w};
            float p = 0.f;
            #pragma unroll
            for (int j = 0; j < 4; j++) {
                float h = b1r[j];
                #pragma unroll
                for (int k = 0; k < 16; k++) h += av[k] * wr[j * 16 + k];
                p += fmaxf(h, 0.f) * w2r[j];
            }
            p += __shfl_xor(p, 1, 64);
            p += __shfl_xor(p, 2, 64);
            p += __shfl_xor(p, 4, 64);
            p += __shfl_xor(p, 8, 64);
            p += __shfl_xor(p, 16, 64);
            if (jg == 0) ptile[le] = p;
        }
        __syncthreads();

        // epilogue: one thread per tile-edge
        int e = ebase + threadIdx.x;
        if (e < EE) {
            float acc = ptile[threadIdx.x] + bias2;
            float sp = fmaxf(acc, 0.f) + log1pf(expf(-fabsf(acc)));
            float w = sp + 1e-6f;
            ew[e] = w;
            int s = src[e];
            atomicAdd(&deg_w[s], w);
            atomicAdd(&deg_c[s], 1.0f);
        }
        __syncthreads();
    }
}

// ============ K2: dis = deg_w^-0.5 ============
__global__ __launch_bounds__(256) void k_dis(const float* __restrict__ deg_w,
                                             float* __restrict__ dis)
{
    int n = blockIdx.x * 256 + threadIdx.x;
    if (n >= NN) return;
    float d = deg_w[n];
    dis[n] = d > 0.f ? 1.f / sqrtf(d) : 0.f;
}

// ============ K3a: per-1024-block exclusive scan of degree counts ============
__global__ __launch_bounds__(1024) void k_scan_block(
    const float* __restrict__ deg_c, int* __restrict__ scanned,
    int* __restrict__ blocksums)
{
    __shared__ int s[1024];
    int i = blockIdx.x * 1024 + threadIdx.x;
    int c = (i < NN) ? (int)deg_c[i] : 0;
    s[threadIdx.x] = c;
    __syncthreads();
    for (int off = 1; off < 1024; off <<= 1) {
        int v = (threadIdx.x >= off) ? s[threadIdx.x - off] : 0;
        __syncthreads();
        s[threadIdx.x] += v;
        __syncthreads();
    }
    if (i < NN) scanned[i] = s[threadIdx.x] - c; // exclusive
    if (threadIdx.x == 1023) blocksums[blockIdx.x] = s[1023];
}

// ============ K3b: scan the block sums (one block) ============
__global__ __launch_bounds__(128) void k_scan_top(int* __restrict__ blocksums)
{
    __shared__ int s[128];
    int c = (threadIdx.x < SCAN_NB) ? blocksums[threadIdx.x] : 0;
    s[threadIdx.x] = c;
    __syncthreads();
    for (int off = 1; off < 128; off <<= 1) {
        int v = (threadIdx.x >= off) ? s[threadIdx.x - off] : 0;
        __syncthreads();
        s[threadIdx.x] += v;
        __syncthreads();
    }
    if (threadIdx.x < SCAN_NB) blocksums[threadIdx.x] = s[threadIdx.x] - c; // exclusive
}

// ============ K3c: rowstart / cursor init ============
__global__ __launch_bounds__(256) void k_cursor(
    const int* __restrict__ scanned, const int* __restrict__ blocksums,
    int* __restrict__ rowstart, int* __restrict__ cur)
{
    int n = blockIdx.x * 256 + threadIdx.x;
    if (n >= NN) return;
    int st = scanned[n] + blocksums[n >> 10];
    rowstart[n] = st;
    cur[n] = st;
}

// ============ K3d: scatter edges into CSR buckets (dst + norm) ============
__global__ __launch_bounds__(256) void k_scatter(
    const int* __restrict__ src, const int* __restrict__ dst,
    const float* __restrict__ ew, const float* __restrict__ dis,
    int* __restrict__ cur, int* __restrict__ csr_dst, float* __restrict__ csr_w)
{
    int e = blockIdx.x * 256 + threadIdx.x;
    if (e >= EE) return;
    int s = src[e], d = dst[e];
    float w = dis[s] * ew[e] * dis[d];
    int pos = atomicAdd(&cur[s], 1);
    csr_dst[pos] = d;
    csr_w[pos] = w;
}

// ============ K3e: fused diffusion gather + cosine + log-degree ============
__global__ __launch_bounds__(256) void k_gather_cos(
    const int* __restrict__ rowstart, const float* __restrict__ deg_c,
    const int* __restrict__ csr_dst, const float* __restrict__ csr_w,
    const float* __restrict__ x, float* __restrict__ raw0, float* __restrict__ raw2)
{
    int node = (blockIdx.x * 256 + threadIdx.x) >> 6;
    int lane = threadIdx.x & 63;
    if (node >= NN) return;
    int start = rowstart[node];
    int deg = (int)deg_c[node];
    const float2* xp = (const float2*)x;
    float2 xn = xp[(size_t)node * 64 + lane];
    float2 acc = {0.f, 0.f};
    for (int base = 0; base < deg; base += 64) {
        int rem = deg - base; if (rem > 64) rem = 64;
        int md = 0; float mw = 0.f;
        if (lane < rem) {
            md = csr_dst[start + base + lane];
            mw = csr_w[start + base + lane];
        }
        int e = 0;
        for (; e + 4 <= rem; e += 4) {
            int d0 = __shfl(md, e, 64),   d1 = __shfl(md, e+1, 64);
            int d2 = __shfl(md, e+2, 64), d3 = __shfl(md, e+3, 64);
            float w0 = __shfl(mw, e, 64),   w1 = __shfl(mw, e+1, 64);
            float w2 = __shfl(mw, e+2, 64), w3 = __shfl(mw, e+3, 64);
            float2 v0 = xp[(size_t)d0 * 64 + lane];
            float2 v1 = xp[(size_t)d1 * 64 + lane];
            float2 v2 = xp[(size_t)d2 * 64 + lane];
            float2 v3 = xp[(size_t)d3 * 64 + lane];
            acc.x += w0 * v0.x; acc.y += w0 * v0.y;
            acc.x += w1 * v1.x; acc.y += w1 * v1.y;
            acc.x += w2 * v2.x; acc.y += w2 * v2.y;
            acc.x += w3 * v3.x; acc.y += w3 * v3.y;
        }
        for (; e < rem; e++) {
            int d = __shfl(md, e, 64);
            float w = __shfl(mw, e, 64);
            float2 v = xp[(size_t)d * 64 + lane];
            acc.x += w * v.x; acc.y += w * v.y;
        }
    }
    float dot = xn.x * acc.x + xn.y * acc.y;
    float nx  = xn.x * xn.x + xn.y * xn.y;
    float nd  = acc.x * acc.x + acc.y * acc.y;
    #pragma unroll
    for (int off = 32; off; off >>= 1) {
        dot += __shfl_xor(dot, off, 64);
        nx  += __shfl_xor(nx,  off, 64);
        nd  += __shfl_xor(nd,  off, 64);
    }
    if (lane == 0) {
        raw2[node] = dot / ((sqrtf(nx) + 1e-6f) * (sqrtf(nd) + 1e-6f));
        raw0[node] = logf((float)deg + 1.0f);
    }
}

// ============ K4: per-node feat MLP (register-blocked GEMM) ============
#define XSTR 132
__global__ __launch_bounds__(256) void k_node(
    const float* __restrict__ x,
    const float* __restrict__ W1, const float* __restrict__ b1,
    const float* __restrict__ W2, const float* __restrict__ b2,
    float* __restrict__ raw1)
{
    __shared__ float xs[64 * XSTR]; // 33.8 KB
    int wave = threadIdx.x >> 6, lane = threadIdx.x & 63;
    int ng = lane >> 4, jg = lane & 15;
    int blockBase = blockIdx.x * 64;

    #pragma unroll
    for (int it = 0; it < 8; it++) {
        int s = threadIdx.x + 256 * it;
        int row = s >> 5, c4 = s & 31;
        int gn = blockBase + row; if (gn >= NN) gn = NN - 1;
        *(float4*)(xs + row * XSTR + c4 * 4) =
            *(const float4*)(x + (size_t)gn * DD + c4 * 4);
    }
    __syncthreads();

    const float* xw = xs + (wave * 16 + ng * 4) * XSTR;
    int j0 = jg * 8;
    float acc[4][8];
    #pragma unroll
    for (int i = 0; i < 4; i++)
        #pragma unroll
        for (int jj = 0; jj < 8; jj++) acc[i][jj] = 0.f;

    for (int k = 0; k < DD; k += 4) {
        float4 xv[4];
        #pragma unroll
        for (int i = 0; i < 4; i++) xv[i] = *(const float4*)(xw + i * XSTR + k);
        float4 wv[4][2];
        #pragma unroll
        for (int kk = 0; kk < 4; kk++) {
            wv[kk][0] = *(const float4*)(W1 + (k + kk) * DD + j0);
            wv[kk][1] = *(const float4*)(W1 + (k + kk) * DD + j0 + 4);
        }
        #pragma unroll
        for (int i = 0; i < 4; i++) {
            const float xe[4] = {xv[i].x, xv[i].y, xv[i].z, xv[i].w};
            #pragma unroll
            for (int kk = 0; kk < 4; kk++) {
                acc[i][0] += xe[kk] * wv[kk][0].x;
                acc[i][1] += xe[kk] * wv[kk][0].y;
                acc[i][2] += xe[kk] * wv[kk][0].z;
                acc[i][3] += xe[kk] * wv[kk][0].w;
                acc[i][4] += xe[kk] * wv[kk][1].x;
                acc[i][5] += xe[kk] * wv[kk][1].y;
                acc[i][6] += xe[kk] * wv[kk][1].z;
                acc[i][7] += xe[kk] * wv[kk][1].w;
            }
        }
    }

    float4 b1a = *(const float4*)(b1 + j0), b1b = *(const float4*)(b1 + j0 + 4);
    float4 w2a = *(const float4*)(W2 + j0), w2b = *(const float4*)(W2 + j0 + 4);
    const float b1v[8] = {b1a.x,b1a.y,b1a.z,b1a.w, b1b.x,b1b.y,b1b.z,b1b.w};
    const float w2v[8] = {w2a.x,w2a.y,w2a.z,w2a.w, w2b.x,w2b.y,w2b.z,w2b.w};
    float bias2 = b2[0];
    #pragma unroll
    for (int i = 0; i < 4; i++) {
        float p = 0.f;
        #pragma unroll
        for (int jj = 0; jj < 8; jj++)
            p += fmaxf(acc[i][jj] + b1v[jj], 0.f) * w2v[jj];
        p += __shfl_xor(p, 1, 64);
        p += __shfl_xor(p, 2, 64);
        p += __shfl_xor(p, 4, 64);
        p += __shfl_xor(p, 8, 64);
        int node = blockBase + wave * 16 + ng * 4 + i;
        if (jg == 0 && node < NN) raw1[node] = p + bias2;
    }
}

// ============ K5: block-level f64 partial sums (sum, sumsq) x3 ============
__global__ __launch_bounds__(256) void k_reduce(
    const float* __restrict__ r0, const float* __restrict__ r1,
    const float* __restrict__ r2, double* __restrict__ partials)
{
    __shared__ double sd[256];
    double s[6] = {0,0,0,0,0,0};
    for (int n = blockIdx.x * 256 + threadIdx.x; n < NN; n += 256 * NRED) {
        double v0 = r0[n], v1 = r1[n], v2 = r2[n];
        s[0] += v0; s[1] += v0*v0;
        s[2] += v1; s[3] += v1*v1;
        s[4] += v2; s[5] += v2*v2;
    }
    for (int q = 0; q < 6; q++) {
        sd[threadIdx.x] = s[q];
        __syncthreads();
        for (int off = 128; off; off >>= 1) {
            if (threadIdx.x < off) sd[threadIdx.x] += sd[threadIdx.x + off];
            __syncthreads();
        }
        if (threadIdx.x == 0) partials[blockIdx.x * 6 + q] = sd[0];
        __syncthreads();
    }
}

// ============ K6: final stats -> mean, 1/(std+eps) per view ============
__global__ __launch_bounds__(256) void k_stats(const double* __restrict__ partials,
                                               float* __restrict__ stats)
{
    __shared__ double sd[256];
    __shared__ double sums[6];
    for (int q = 0; q < 6; q++) {
        sd[threadIdx.x] = (threadIdx.x < NRED) ? partials[threadIdx.x * 6 + q] : 0.0;
        __syncthreads();
        for (int off = 128; off; off >>= 1) {
            if (threadIdx.x < off) sd[threadIdx.x] += sd[threadIdx.x + off];
            __syncthreads();
        }
        if (threadIdx.x == 0) sums[q] = sd[0];
        __syncthreads();
    }
    if (threadIdx.x == 0) {
        for (int i = 0; i < 3; i++) {
            double sum = sums[2*i], sq = sums[2*i+1];
            double mean = sum / NN;
            double var = (sq - sum * sum / NN) / (NN - 1);
            double sdv = sqrt(var > 0 ? var : 0);
            stats[2*i]   = (float)mean;
            stats[2*i+1] = (float)(1.0 / (sdv + 1e-6));
        }
    }
}

// ============ K7: score = sigmoid(z @ vw) ============
__global__ __launch_bounds__(256) void k_score(
    const float* __restrict__ r0, const float* __restrict__ r1,
    const float* __restrict__ r2, const float* __restrict__ stats,
    const float* __restrict__ vw, float* __restrict__ score)
{
    int n = blockIdx.x * 256 + threadIdx.x;
    if (n >= NN) return;
    float z0 = (r0[n] - stats[0]) * stats[1];
    float z1 = (r1[n] - stats[2]) * stats[3];
    float z2 = (r2[n] - stats[4]) * stats[5];
    float r = z0 * vw[0] + z1 * vw[1] + z2 * vw[2];
    score[n] = 1.f / (1.f + expf(-r));
}

// ============ K8: per-graph top-K via bitonic sort of 2048 keys ============
__global__ __launch_bounds__(1024) void k_topk(
    const float* __restrict__ score, int* __restrict__ keep,
    int* __restrict__ new_id, float* __restrict__ obatch)
{
    __shared__ unsigned long long keys[2048];
    int b = blockIdx.x;
    unsigned t = threadIdx.x;
    for (unsigned i = t; i < 2048; i += 1024) {
        unsigned long long kk = 0ull;
        if (i < NPG) {
            float sc = score[b * NPG + i];
            kk = ((unsigned long long)__float_as_uint(sc) << 32)
               | (unsigned long long)(0xFFFFFFFFu - i);
        }
        keys[i] = kk;
    }
    __syncthreads();
    for (unsigned k = 2; k <= 2048; k <<= 1) {
        for (unsigned j = k >> 1; j > 0; j >>= 1) {
            unsigned i = ((t & ~(j - 1)) << 1) | (t & (j - 1));
            unsigned p = i | j;
            unsigned long long a = keys[i], c = keys[p];
            bool up = ((i & k) == 0);
            if ((a < c) == up) { keys[i] = c; keys[p] = a; }
            __syncthreads();
        }
    }
    if (t < KK) {
        unsigned long long kk = keys[t];
        unsigned li = 0xFFFFFFFFu - (unsigned)(kk & 0xFFFFFFFFu);
        int node = b * NPG + (int)li;
        int j = b * KK + (int)t;
        keep[j] = node;
        new_id[node] = j;
        obatch[j] = (float)b;
    }
}

// ============ K9: out_x = x[keep] * score[keep] ============
__global__ __launch_bounds__(128) void k_outx(
    const float* __restrict__ x, const float* __restrict__ score,
    const int* __restrict__ keep, float* __restrict__ out_x)
{
    int j = blockIdx.x;
    int node = keep[j];
    float s = score[node];
    out_x[(size_t)j * DD + threadIdx.x] = x[(size_t)node * DD + threadIdx.x] * s;
}

// ============ K10a: edge mask + new edge_index ============
__global__ __launch_bounds__(256) void k_edges(
    const int* __restrict__ src, const int* __restrict__ dst,
    const int* __restrict__ new_id, float* __restrict__ oei,
    float* __restrict__ emask)
{
    int e = blockIdx.x * 256 + threadIdx.x;
    if (e >= EE) return;
    int ns = new_id[src[e]], nd = new_id[dst[e]];
    bool m = (ns >= 0) && (nd >= 0);
    oei[e]      = m ? (float)ns : 0.f;
    oei[EE + e] = m ? (float)nd : 0.f;
    emask[e]    = m ? 1.f : 0.f;
}

// ============ K10b: masked edge_attr copy (float4) ============
__global__ __launch_bounds__(256) void k_attr(
    const float* __restrict__ edge_attr, const float* __restrict__ emask,
    float* __restrict__ oea)
{
    int idx = blockIdx.x * 256 + threadIdx.x;
    if (idx >= EE * 4) return;
    int e = idx >> 2;
    float m = emask[e];
    float4 v = ((const float4*)edge_attr)[idx];
    float4 o; o.x = v.x*m; o.y = v.y*m; o.z = v.z*m; o.w = v.w*m;
    ((float4*)oea)[idx] = o;
}

extern "C" void kernel_launch(void* const* d_in, const int* in_sizes, int n_in,
                              void* d_out, int out_size, void* d_ws, size_t ws_size,
                              hipStream_t stream) {
    const float* x         = (const float*)d_in[0];
    const int*   edge_idx  = (const int*)d_in[1];
    const float* edge_attr = (const float*)d_in[2];
    const float* W1  = (const float*)d_in[4];
    const float* b1  = (const float*)d_in[5];
    const float* W2  = (const float*)d_in[6];
    const float* b2  = (const float*)d_in[7];
    const float* We1 = (const float*)d_in[8];
    const float* be1 = (const float*)d_in[9];
    const float* We2 = (const float*)d_in[10];
    const float* be2 = (const float*)d_in[11];
    const float* vw  = (const float*)d_in[12];

    const int* src = edge_idx;
    const int* dst = edge_idx + EE;

    float* out    = (float*)d_out;
    float* out_x  = out;
    float* oei    = out + OFF_OEI;
    float* oea    = out + OFF_OEA;
    float* obatch = out + OFF_OBATCH;
    float* emask  = out + OFF_EMASK;

    // scratch inside d_out (dead before any output writer runs)
    int*   csr_dst   = (int*)(out + 12800000);    // 600k
    float* csr_w     = out + 13400000;            // 600k
    int*   rowstart  = (int*)(out + 14000000);    // 100k
    int*   cur       = (int*)(out + 14100000);    // 100k
    int*   scanned   = (int*)(out + 14200000);    // 100k
    int*   blocksums = (int*)(out + 14300000);    // 256

    // workspace layout (floats) — ~5.9 MB total
    float* ws     = (float*)d_ws;
    float* ew     = ws;                     // 600000
    float* deg_w  = ws + 600000;            // 100000
    float* deg_c  = ws + 700000;            // 100000 (adjacent to deg_w)
    float* dis    = ws + 800000;            // 100000
    float* score  = ws + 900000;            // 100000
    float* raw0   = ws + 1000000;           // 100000
    float* raw1   = ws + 1100000;           // 100000
    float* raw2   = ws + 1200000;           // 100000
    int*   keep   = (int*)(ws + 1300000);   // 50000
    int*   new_id = (int*)(ws + 1350000);   // 100000
    double* partials = (double*)(ws + 1450000); // NRED*6 doubles
    float* stats  = ws + 1450000 + 2 * 6 * NRED; // 6 floats

    hipMemsetAsync(deg_w, 0, 2 * NN * sizeof(float), stream); // deg_w + deg_c
    hipMemsetAsync(new_id, 0xFF, NN * sizeof(int), stream);   // -1

    k_edge_mlp<<<EMLP_GRID, 256, 0, stream>>>(edge_attr, src, We1, be1,
                                              We2, be2, ew, deg_w, deg_c);
    k_dis<<<(NN + 255) / 256, 256, 0, stream>>>(deg_w, dis);
    // CSR build
    k_scan_block<<<SCAN_NB, 1024, 0, stream>>>(deg_c, scanned, blocksums);
    k_scan_top<<<1, 128, 0, stream>>>(blocksums);
    k_cursor<<<(NN + 255) / 256, 256, 0, stream>>>(scanned, blocksums, rowstart, cur);
    k_scatter<<<(EE + 255) / 256, 256, 0, stream>>>(src, dst, ew, dis, cur, csr_dst, csr_w);
    // fused diffusion gather + cosine + log-degree (x_diff never materialized)
    k_gather_cos<<<(NN * 64 + 255) / 256, 256, 0, stream>>>(rowstart, deg_c, csr_dst,
                                                            csr_w, x, raw0, raw2);
    k_node<<<(NN + 63) / 64, 256, 0, stream>>>(x, W1, b1, W2, b2, raw1);
    k_reduce<<<NRED, 256, 0, stream>>>(raw0, raw1, raw2, partials);
    k_stats<<<1, 256, 0, stream>>>(partials, stats);
    k_score<<<(NN + 255) / 256, 256, 0, stream>>>(raw0, raw1, raw2, stats, vw, score);
    k_topk<<<BB, 1024, 0, stream>>>(score, keep, new_id, obatch);
    k_outx<<<NKEEP, 128, 0, stream>>>(x, score, keep, out_x);
    k_edges<<<(EE + 255) / 256, 256, 0, stream>>>(src, dst, new_id, oei, emask);
    k_attr<<<(EE * 4 + 255) / 256, 256, 0, stream>>>(edge_attr, emask, oea);
}

// Round 6
// 431.622 us; speedup vs baseline: 1.1875x; 1.0098x over previous
//
#include <hip/hip_runtime.h>
#include <math.h>

// ---- problem constants (match reference) ----
#define NN   100000   // nodes
#define DD   128      // in_channels
#define EE   600000   // edges
#define EAD  16       // edge_attr dim
#define BB   50       // graphs
#define NPG  2000     // nodes per graph
#define KK   1000     // kept per graph
#define NKEEP (BB*KK) // 50000

// output layout (floats, concatenated in return order)
#define OFF_OEI    6400000
#define OFF_OEA    7600000
#define OFF_OBATCH 17200000
#define OFF_EMASK  17250000

#define NRED 240  // reduction blocks
#define SCAN_NB 98 // ceil(100000/1024)

// ============ K1: edge MLP -> ew, deg_w, deg_c ============
// 1 thread = 1 edge (all 128 j). edge_attr tile staged in LDS (stride 20 ->
// conflict-free b128 row reads); We1^T in LDS read as broadcast b128 (free).
// Full 2344-block grid for occupancy. No shuffles.
#define EASTR 20
__global__ __launch_bounds__(256) void k_edge_mlp(
    const float* __restrict__ edge_attr, const int* __restrict__ src,
    const float* __restrict__ We1, const float* __restrict__ be1,
    const float* __restrict__ We2, const float* __restrict__ be2,
    float* __restrict__ ew, float* __restrict__ deg_w, float* __restrict__ deg_c)
{
    __shared__ float ea[256 * EASTR];  // 20.5 KB
    __shared__ float wt[2048];         // wt[j*16+k] = We1[k][j]  (8 KB)
    __shared__ float b1s[128];
    __shared__ float w2s[128];
    int tid = threadIdx.x;
    int ebase = blockIdx.x * 256;

    // stage We1^T: thread j (j<128) reads column j coalesced, writes row j*16
    if (tid < 128) {
        float tmp[16];
        #pragma unroll
        for (int k = 0; k < 16; k++) tmp[k] = We1[k * DD + tid];
        #pragma unroll
        for (int c = 0; c < 4; c++)
            *(float4*)(wt + tid * 16 + c * 4) =
                make_float4(tmp[4*c], tmp[4*c+1], tmp[4*c+2], tmp[4*c+3]);
        b1s[tid] = be1[tid];
        w2s[tid] = We2[tid];
    }
    // stage edge-attr tile (coalesced float4)
    #pragma unroll
    for (int it = 0; it < 4; it++) {
        int idx = tid + 256 * it;                 // float4 slot 0..1023
        long long g = (long long)ebase * 4 + idx;
        long long maxg = (long long)EE * 4;
        if (g >= maxg) g = maxg - 1;
        float4 v = ((const float4*)edge_attr)[g];
        int le = idx >> 2, c = idx & 3;
        *(float4*)(ea + le * EASTR + c * 4) = v;
    }
    __syncthreads();

    // own edge row -> 16 VGPRs (stride-20 b128: conflict-free)
    float av[16];
    {
        const float* a = ea + tid * EASTR;
        float4 a0 = *(const float4*)(a);
        float4 a1 = *(const float4*)(a + 4);
        float4 a2 = *(const float4*)(a + 8);
        float4 a3 = *(const float4*)(a + 12);
        av[0]=a0.x; av[1]=a0.y; av[2]=a0.z; av[3]=a0.w;
        av[4]=a1.x; av[5]=a1.y; av[6]=a1.z; av[7]=a1.w;
        av[8]=a2.x; av[9]=a2.y; av[10]=a2.z; av[11]=a2.w;
        av[12]=a3.x; av[13]=a3.y; av[14]=a3.z; av[15]=a3.w;
    }

    float acc = 0.f;
    #pragma unroll 4
    for (int j = 0; j < DD; j++) {
        float4 w0 = *(const float4*)(wt + j * 16);
        float4 w1 = *(const float4*)(wt + j * 16 + 4);
        float4 w2 = *(const float4*)(wt + j * 16 + 8);
        float4 w3 = *(const float4*)(wt + j * 16 + 12);
        float h = b1s[j];
        h += av[0]*w0.x;  h += av[1]*w0.y;  h += av[2]*w0.z;  h += av[3]*w0.w;
        h += av[4]*w1.x;  h += av[5]*w1.y;  h += av[6]*w1.z;  h += av[7]*w1.w;
        h += av[8]*w2.x;  h += av[9]*w2.y;  h += av[10]*w2.z; h += av[11]*w2.w;
        h += av[12]*w3.x; h += av[13]*w3.y; h += av[14]*w3.z; h += av[15]*w3.w;
        acc += fmaxf(h, 0.f) * w2s[j];
    }

    int e = ebase + tid;
    if (e < EE) {
        float a = acc + be2[0];
        float sp = fmaxf(a, 0.f) + log1pf(expf(-fabsf(a)));
        float w = sp + 1e-6f;
        ew[e] = w;
        int s = src[e];
        atomicAdd(&deg_w[s], w);
        atomicAdd(&deg_c[s], 1.0f);
    }
}

// ============ K2: dis = deg_w^-0.5 ============
__global__ __launch_bounds__(256) void k_dis(const float* __restrict__ deg_w,
                                             float* __restrict__ dis)
{
    int n = blockIdx.x * 256 + threadIdx.x;
    if (n >= NN) return;
    float d = deg_w[n];
    dis[n] = d > 0.f ? 1.f / sqrtf(d) : 0.f;
}

// ============ K3a: per-1024-block exclusive scan of degree counts ============
__global__ __launch_bounds__(1024) void k_scan_block(
    const float* __restrict__ deg_c, int* __restrict__ scanned,
    int* __restrict__ blocksums)
{
    __shared__ int s[1024];
    int i = blockIdx.x * 1024 + threadIdx.x;
    int c = (i < NN) ? (int)deg_c[i] : 0;
    s[threadIdx.x] = c;
    __syncthreads();
    for (int off = 1; off < 1024; off <<= 1) {
        int v = (threadIdx.x >= off) ? s[threadIdx.x - off] : 0;
        __syncthreads();
        s[threadIdx.x] += v;
        __syncthreads();
    }
    if (i < NN) scanned[i] = s[threadIdx.x] - c; // exclusive
    if (threadIdx.x == 1023) blocksums[blockIdx.x] = s[1023];
}

// ============ K3b: scan the block sums (one block) ============
__global__ __launch_bounds__(128) void k_scan_top(int* __restrict__ blocksums)
{
    __shared__ int s[128];
    int c = (threadIdx.x < SCAN_NB) ? blocksums[threadIdx.x] : 0;
    s[threadIdx.x] = c;
    __syncthreads();
    for (int off = 1; off < 128; off <<= 1) {
        int v = (threadIdx.x >= off) ? s[threadIdx.x - off] : 0;
        __syncthreads();
        s[threadIdx.x] += v;
        __syncthreads();
    }
    if (threadIdx.x < SCAN_NB) blocksums[threadIdx.x] = s[threadIdx.x] - c; // exclusive
}

// ============ K3c: rowstart / cursor init ============
__global__ __launch_bounds__(256) void k_cursor(
    const int* __restrict__ scanned, const int* __restrict__ blocksums,
    int* __restrict__ rowstart, int* __restrict__ cur)
{
    int n = blockIdx.x * 256 + threadIdx.x;
    if (n >= NN) return;
    int st = scanned[n] + blocksums[n >> 10];
    rowstart[n] = st;
    cur[n] = st;
}

// ============ K3d: scatter edges into CSR buckets (dst + norm) ============
__global__ __launch_bounds__(256) void k_scatter(
    const int* __restrict__ src, const int* __restrict__ dst,
    const float* __restrict__ ew, const float* __restrict__ dis,
    int* __restrict__ cur, int* __restrict__ csr_dst, float* __restrict__ csr_w)
{
    int e = blockIdx.x * 256 + threadIdx.x;
    if (e >= EE) return;
    int s = src[e], d = dst[e];
    float w = dis[s] * ew[e] * dis[d];
    int pos = atomicAdd(&cur[s], 1);
    csr_dst[pos] = d;
    csr_w[pos] = w;
}

// ============ K3e: fused diffusion gather + cosine + log-degree ============
// XCD-aware swizzle: blockIdx%8 ~ XCD -> each XCD works a contiguous
// 12500-node slice (3.2 MB of x fits the 4 MB per-XCD L2).
__global__ __launch_bounds__(256) void k_gather_cos(
    const int* __restrict__ rowstart, const float* __restrict__ deg_c,
    const int* __restrict__ csr_dst, const float* __restrict__ csr_w,
    const float* __restrict__ x, float* __restrict__ raw0, float* __restrict__ raw2)
{
    int blk = blockIdx.x;                       // 25000 blocks
    int node = ((blk & 7) * 3125 + (blk >> 3)) * 4 + (threadIdx.x >> 6);
    int lane = threadIdx.x & 63;
    if (node >= NN) return;
    int start = rowstart[node];
    int deg = (int)deg_c[node];
    const float2* xp = (const float2*)x;
    float2 xn = xp[(size_t)node * 64 + lane];
    float2 acc = {0.f, 0.f};
    for (int base = 0; base < deg; base += 64) {
        int rem = deg - base; if (rem > 64) rem = 64;
        int md = 0; float mw = 0.f;
        if (lane < rem) {
            md = csr_dst[start + base + lane];
            mw = csr_w[start + base + lane];
        }
        int e = 0;
        for (; e + 4 <= rem; e += 4) {
            int d0 = __shfl(md, e, 64),   d1 = __shfl(md, e+1, 64);
            int d2 = __shfl(md, e+2, 64), d3 = __shfl(md, e+3, 64);
            float w0 = __shfl(mw, e, 64),   w1 = __shfl(mw, e+1, 64);
            float w2 = __shfl(mw, e+2, 64), w3 = __shfl(mw, e+3, 64);
            float2 v0 = xp[(size_t)d0 * 64 + lane];
            float2 v1 = xp[(size_t)d1 * 64 + lane];
            float2 v2 = xp[(size_t)d2 * 64 + lane];
            float2 v3 = xp[(size_t)d3 * 64 + lane];
            acc.x += w0 * v0.x; acc.y += w0 * v0.y;
            acc.x += w1 * v1.x; acc.y += w1 * v1.y;
            acc.x += w2 * v2.x; acc.y += w2 * v2.y;
            acc.x += w3 * v3.x; acc.y += w3 * v3.y;
        }
        for (; e < rem; e++) {
            int d = __shfl(md, e, 64);
            float w = __shfl(mw, e, 64);
            float2 v = xp[(size_t)d * 64 + lane];
            acc.x += w * v.x; acc.y += w * v.y;
        }
    }
    float dot = xn.x * acc.x + xn.y * acc.y;
    float nx  = xn.x * xn.x + xn.y * xn.y;
    float nd  = acc.x * acc.x + acc.y * acc.y;
    #pragma unroll
    for (int off = 32; off; off >>= 1) {
        dot += __shfl_xor(dot, off, 64);
        nx  += __shfl_xor(nx,  off, 64);
        nd  += __shfl_xor(nd,  off, 64);
    }
    if (lane == 0) {
        raw2[node] = dot / ((sqrtf(nx) + 1e-6f) * (sqrtf(nd) + 1e-6f));
        raw0[node] = logf((float)deg + 1.0f);
    }
}

// ============ K4: per-node feat MLP (register-blocked GEMM) ============
#define XSTR 132
__global__ __launch_bounds__(256) void k_node(
    const float* __restrict__ x,
    const float* __restrict__ W1, const float* __restrict__ b1,
    const float* __restrict__ W2, const float* __restrict__ b2,
    float* __restrict__ raw1)
{
    __shared__ float xs[64 * XSTR]; // 33.8 KB
    int wave = threadIdx.x >> 6, lane = threadIdx.x & 63;
    int ng = lane >> 4, jg = lane & 15;
    int blockBase = blockIdx.x * 64;

    #pragma unroll
    for (int it = 0; it < 8; it++) {
        int s = threadIdx.x + 256 * it;
        int row = s >> 5, c4 = s & 31;
        int gn = blockBase + row; if (gn >= NN) gn = NN - 1;
        *(float4*)(xs + row * XSTR + c4 * 4) =
            *(const float4*)(x + (size_t)gn * DD + c4 * 4);
    }
    __syncthreads();

    const float* xw = xs + (wave * 16 + ng * 4) * XSTR;
    int j0 = jg * 8;
    float acc[4][8];
    #pragma unroll
    for (int i = 0; i < 4; i++)
        #pragma unroll
        for (int jj = 0; jj < 8; jj++) acc[i][jj] = 0.f;

    for (int k = 0; k < DD; k += 4) {
        float4 xv[4];
        #pragma unroll
        for (int i = 0; i < 4; i++) xv[i] = *(const float4*)(xw + i * XSTR + k);
        float4 wv[4][2];
        #pragma unroll
        for (int kk = 0; kk < 4; kk++) {
            wv[kk][0] = *(const float4*)(W1 + (k + kk) * DD + j0);
            wv[kk][1] = *(const float4*)(W1 + (k + kk) * DD + j0 + 4);
        }
        #pragma unroll
        for (int i = 0; i < 4; i++) {
            const float xe[4] = {xv[i].x, xv[i].y, xv[i].z, xv[i].w};
            #pragma unroll
            for (int kk = 0; kk < 4; kk++) {
                acc[i][0] += xe[kk] * wv[kk][0].x;
                acc[i][1] += xe[kk] * wv[kk][0].y;
                acc[i][2] += xe[kk] * wv[kk][0].z;
                acc[i][3] += xe[kk] * wv[kk][0].w;
                acc[i][4] += xe[kk] * wv[kk][1].x;
                acc[i][5] += xe[kk] * wv[kk][1].y;
                acc[i][6] += xe[kk] * wv[kk][1].z;
                acc[i][7] += xe[kk] * wv[kk][1].w;
            }
        }
    }

    float4 b1a = *(const float4*)(b1 + j0), b1b = *(const float4*)(b1 + j0 + 4);
    float4 w2a = *(const float4*)(W2 + j0), w2b = *(const float4*)(W2 + j0 + 4);
    const float b1v[8] = {b1a.x,b1a.y,b1a.z,b1a.w, b1b.x,b1b.y,b1b.z,b1b.w};
    const float w2v[8] = {w2a.x,w2a.y,w2a.z,w2a.w, w2b.x,w2b.y,w2b.z,w2b.w};
    float bias2 = b2[0];
    #pragma unroll
    for (int i = 0; i < 4; i++) {
        float p = 0.f;
        #pragma unroll
        for (int jj = 0; jj < 8; jj++)
            p += fmaxf(acc[i][jj] + b1v[jj], 0.f) * w2v[jj];
        p += __shfl_xor(p, 1, 64);
        p += __shfl_xor(p, 2, 64);
        p += __shfl_xor(p, 4, 64);
        p += __shfl_xor(p, 8, 64);
        int node = blockBase + wave * 16 + ng * 4 + i;
        if (jg == 0 && node < NN) raw1[node] = p + bias2;
    }
}

// ============ K5: block-level f64 partial sums (sum, sumsq) x3 ============
__global__ __launch_bounds__(256) void k_reduce(
    const float* __restrict__ r0, const float* __restrict__ r1,
    const float* __restrict__ r2, double* __restrict__ partials)
{
    __shared__ double sd[256];
    double s[6] = {0,0,0,0,0,0};
    for (int n = blockIdx.x * 256 + threadIdx.x; n < NN; n += 256 * NRED) {
        double v0 = r0[n], v1 = r1[n], v2 = r2[n];
        s[0] += v0; s[1] += v0*v0;
        s[2] += v1; s[3] += v1*v1;
        s[4] += v2; s[5] += v2*v2;
    }
    for (int q = 0; q < 6; q++) {
        sd[threadIdx.x] = s[q];
        __syncthreads();
        for (int off = 128; off; off >>= 1) {
            if (threadIdx.x < off) sd[threadIdx.x] += sd[threadIdx.x + off];
            __syncthreads();
        }
        if (threadIdx.x == 0) partials[blockIdx.x * 6 + q] = sd[0];
        __syncthreads();
    }
}

// ============ K6: final stats -> mean, 1/(std+eps) per view ============
__global__ __launch_bounds__(256) void k_stats(const double* __restrict__ partials,
                                               float* __restrict__ stats)
{
    __shared__ double sd[256];
    __shared__ double sums[6];
    for (int q = 0; q < 6; q++) {
        sd[threadIdx.x] = (threadIdx.x < NRED) ? partials[threadIdx.x * 6 + q] : 0.0;
        __syncthreads();
        for (int off = 128; off; off >>= 1) {
            if (threadIdx.x < off) sd[threadIdx.x] += sd[threadIdx.x + off];
            __syncthreads();
        }
        if (threadIdx.x == 0) sums[q] = sd[0];
        __syncthreads();
    }
    if (threadIdx.x == 0) {
        for (int i = 0; i < 3; i++) {
            double sum = sums[2*i], sq = sums[2*i+1];
            double mean = sum / NN;
            double var = (sq - sum * sum / NN) / (NN - 1);
            double sdv = sqrt(var > 0 ? var : 0);
            stats[2*i]   = (float)mean;
            stats[2*i+1] = (float)(1.0 / (sdv + 1e-6));
        }
    }
}

// ============ K7: score = sigmoid(z @ vw) ============
__global__ __launch_bounds__(256) void k_score(
    const float* __restrict__ r0, const float* __restrict__ r1,
    const float* __restrict__ r2, const float* __restrict__ stats,
    const float* __restrict__ vw, float* __restrict__ score)
{
    int n = blockIdx.x * 256 + threadIdx.x;
    if (n >= NN) return;
    float z0 = (r0[n] - stats[0]) * stats[1];
    float z1 = (r1[n] - stats[2]) * stats[3];
    float z2 = (r2[n] - stats[4]) * stats[5];
    float r = z0 * vw[0] + z1 * vw[1] + z2 * vw[2];
    score[n] = 1.f / (1.f + expf(-r));
}

// ============ K8: per-graph top-K via bitonic sort of 2048 keys ============
__global__ __launch_bounds__(1024) void k_topk(
    const float* __restrict__ score, int* __restrict__ keep,
    int* __restrict__ new_id, float* __restrict__ obatch)
{
    __shared__ unsigned long long keys[2048];
    int b = blockIdx.x;
    unsigned t = threadIdx.x;
    for (unsigned i = t; i < 2048; i += 1024) {
        unsigned long long kk = 0ull;
        if (i < NPG) {
            float sc = score[b * NPG + i];
            kk = ((unsigned long long)__float_as_uint(sc) << 32)
               | (unsigned long long)(0xFFFFFFFFu - i);
        }
        keys[i] = kk;
    }
    __syncthreads();
    for (unsigned k = 2; k <= 2048; k <<= 1) {
        for (unsigned j = k >> 1; j > 0; j >>= 1) {
            unsigned i = ((t & ~(j - 1)) << 1) | (t & (j - 1));
            unsigned p = i | j;
            unsigned long long a = keys[i], c = keys[p];
            bool up = ((i & k) == 0);
            if ((a < c) == up) { keys[i] = c; keys[p] = a; }
            __syncthreads();
        }
    }
    if (t < KK) {
        unsigned long long kk = keys[t];
        unsigned li = 0xFFFFFFFFu - (unsigned)(kk & 0xFFFFFFFFu);
        int node = b * NPG + (int)li;
        int j = b * KK + (int)t;
        keep[j] = node;
        new_id[node] = j;
        obatch[j] = (float)b;
    }
}

// ============ K9: out_x = x[keep] * score[keep] ============
__global__ __launch_bounds__(128) void k_outx(
    const float* __restrict__ x, const float* __restrict__ score,
    const int* __restrict__ keep, float* __restrict__ out_x)
{
    int j = blockIdx.x;
    int node = keep[j];
    float s = score[node];
    out_x[(size_t)j * DD + threadIdx.x] = x[(size_t)node * DD + threadIdx.x] * s;
}

// ============ K10a: edge mask + new edge_index ============
__global__ __launch_bounds__(256) void k_edges(
    const int* __restrict__ src, const int* __restrict__ dst,
    const int* __restrict__ new_id, float* __restrict__ oei,
    float* __restrict__ emask)
{
    int e = blockIdx.x * 256 + threadIdx.x;
    if (e >= EE) return;
    int ns = new_id[src[e]], nd = new_id[dst[e]];
    bool m = (ns >= 0) && (nd >= 0);
    oei[e]      = m ? (float)ns : 0.f;
    oei[EE + e] = m ? (float)nd : 0.f;
    emask[e]    = m ? 1.f : 0.f;
}

// ============ K10b: masked edge_attr copy (float4) ============
__global__ __launch_bounds__(256) void k_attr(
    const float* __restrict__ edge_attr, const float* __restrict__ emask,
    float* __restrict__ oea)
{
    int idx = blockIdx.x * 256 + threadIdx.x;
    if (idx >= EE * 4) return;
    int e = idx >> 2;
    float m = emask[e];
    float4 v = ((const float4*)edge_attr)[idx];
    float4 o; o.x = v.x*m; o.y = v.y*m; o.z = v.z*m; o.w = v.w*m;
    ((float4*)oea)[idx] = o;
}

extern "C" void kernel_launch(void* const* d_in, const int* in_sizes, int n_in,
                              void* d_out, int out_size, void* d_ws, size_t ws_size,
                              hipStream_t stream) {
    const float* x         = (const float*)d_in[0];
    const int*   edge_idx  = (const int*)d_in[1];
    const float* edge_attr = (const float*)d_in[2];
    const float* W1  = (const float*)d_in[4];
    const float* b1  = (const float*)d_in[5];
    const float* W2  = (const float*)d_in[6];
    const float* b2  = (const float*)d_in[7];
    const float* We1 = (const float*)d_in[8];
    const float* be1 = (const float*)d_in[9];
    const float* We2 = (const float*)d_in[10];
    const float* be2 = (const float*)d_in[11];
    const float* vw  = (const float*)d_in[12];

    const int* src = edge_idx;
    const int* dst = edge_idx + EE;

    float* out    = (float*)d_out;
    float* out_x  = out;
    float* oei    = out + OFF_OEI;
    float* oea    = out + OFF_OEA;
    float* obatch = out + OFF_OBATCH;
    float* emask  = out + OFF_EMASK;

    // scratch inside d_out (dead before any output writer runs)
    int*   csr_dst   = (int*)(out + 12800000);    // 600k
    float* csr_w     = out + 13400000;            // 600k
    int*   rowstart  = (int*)(out + 14000000);    // 100k
    int*   cur       = (int*)(out + 14100000);    // 100k
    int*   scanned   = (int*)(out + 14200000);    // 100k
    int*   blocksums = (int*)(out + 14300000);    // 256

    // workspace layout (floats) — ~5.9 MB total
    float* ws     = (float*)d_ws;
    float* ew     = ws;                     // 600000
    float* deg_w  = ws + 600000;            // 100000
    float* deg_c  = ws + 700000;            // 100000 (adjacent to deg_w)
    float* dis    = ws + 800000;            // 100000
    float* score  = ws + 900000;            // 100000
    float* raw0   = ws + 1000000;           // 100000
    float* raw1   = ws + 1100000;           // 100000
    float* raw2   = ws + 1200000;           // 100000
    int*   keep   = (int*)(ws + 1300000);   // 50000
    int*   new_id = (int*)(ws + 1350000);   // 100000
    double* partials = (double*)(ws + 1450000); // NRED*6 doubles
    float* stats  = ws + 1450000 + 2 * 6 * NRED; // 6 floats

    hipMemsetAsync(deg_w, 0, 2 * NN * sizeof(float), stream); // deg_w + deg_c
    hipMemsetAsync(new_id, 0xFF, NN * sizeof(int), stream);   // -1

    k_edge_mlp<<<(EE + 255) / 256, 256, 0, stream>>>(edge_attr, src, We1, be1,
                                                     We2, be2, ew, deg_w, deg_c);
    k_dis<<<(NN + 255) / 256, 256, 0, stream>>>(deg_w, dis);
    // CSR build
    k_scan_block<<<SCAN_NB, 1024, 0, stream>>>(deg_c, scanned, blocksums);
    k_scan_top<<<1, 128, 0, stream>>>(blocksums);
    k_cursor<<<(NN + 255) / 256, 256, 0, stream>>>(scanned, blocksums, rowstart, cur);
    k_scatter<<<(EE + 255) / 256, 256, 0, stream>>>(src, dst, ew, dis, cur, csr_dst, csr_w);
    // fused diffusion gather + cosine + log-degree (x_diff never materialized)
    k_gather_cos<<<(NN * 64 + 255) / 256, 256, 0, stream>>>(rowstart, deg_c, csr_dst,
                                                            csr_w, x, raw0, raw2);
    k_node<<<(NN + 63) / 64, 256, 0, stream>>>(x, W1, b1, W2, b2, raw1);
    k_reduce<<<NRED, 256, 0, stream>>>(raw0, raw1, raw2, partials);
    k_stats<<<1, 256, 0, stream>>>(partials, stats);
    k_score<<<(NN + 255) / 256, 256, 0, stream>>>(raw0, raw1, raw2, stats, vw, score);
    k_topk<<<BB, 1024, 0, stream>>>(score, keep, new_id, obatch);
    k_outx<<<NKEEP, 128, 0, stream>>>(x, score, keep, out_x);
    k_edges<<<(EE + 255) / 256, 256, 0, stream>>>(src, dst, new_id, oei, emask);
    k_attr<<<(EE * 4 + 255) / 256, 256, 0, stream>>>(edge_attr, emask, oea);
}